// Round 6
// baseline (685.025 us; speedup 1.0000x reference)
//
#include <hip/hip_runtime.h>
#include <hip/hip_bf16.h>
#include <stdint.h>

#define B_    2
#define S_    4096
#define D_    768
#define H_    12
#define DH_   64
#define BH_   (B_*H_)
#define M_    (B_*S_)       // 8192
#define NQKV_ 2304
// 1/sqrt(64) * log2(e): Q pre-scaled so softmax runs in exp2 space
#define QSCALE_ 0.18033688011112042f

typedef unsigned short bf16u;
typedef short bf16x8 __attribute__((ext_vector_type(8)));
typedef float f32x4 __attribute__((ext_vector_type(4)));

__device__ __forceinline__ bf16u f2bf(float f) {
    unsigned u = __float_as_uint(f);
    u += 0x7FFFu + ((u >> 16) & 1u);   // round-to-nearest-even
    return (bf16u)(u >> 16);
}

__device__ __forceinline__ unsigned f2bf_pk(float a, float b) {
    return (unsigned)f2bf(a) | ((unsigned)f2bf(b) << 16);
}

__device__ __forceinline__ void gl_lds16(const void* g, void* l) {
    __builtin_amdgcn_global_load_lds(
        (const __attribute__((address_space(1))) unsigned*)g,
        (__attribute__((address_space(3))) unsigned*)l, 16, 0, 0);
}

// ---------------------------------------------------------------- convert
// three tensors in one launch (boundaries are multiples of 256 quads)
#define N1Q_ 1572864   // x      quads
#define N2Q_  442368   // W_qkv  quads
#define N3Q_  147456   // W_out  quads
__global__ __launch_bounds__(256) void convert3_kernel(
    const float* __restrict__ s1, const float* __restrict__ s2,
    const float* __restrict__ s3, bf16u* __restrict__ d1,
    bf16u* __restrict__ d2, bf16u* __restrict__ d3)
{
    int i = blockIdx.x * 256 + threadIdx.x;
    const float* s; bf16u* d; int j;
    if (i < N1Q_)              { s = s1; d = d1; j = i; }
    else if (i < N1Q_ + N2Q_)  { s = s2; d = d2; j = i - N1Q_; }
    else                       { s = s3; d = d3; j = i - N1Q_ - N2Q_; }
    float4 v = ((const float4*)s)[j];
    ushort4 o;
    o.x = f2bf(v.x); o.y = f2bf(v.y); o.z = f2bf(v.z); o.w = f2bf(v.w);
    ((ushort4*)d)[j] = o;
}

// ---------------------------------------------------------------- GEMM
// (unchanged from R5: double-buffered, 1 barrier/k-step, XCD swizzle,
//  V packed uint2 in EPI=1 epilogue)
template<int EPI>
__global__ __launch_bounds__(256) void gemm_kernel(
    const bf16u* __restrict__ A, const bf16u* __restrict__ Bw,
    const float* __restrict__ bias, float* __restrict__ Cout,
    bf16u* __restrict__ Qb, bf16u* __restrict__ Kb, bf16u* __restrict__ Vtb)
{
    __shared__ bf16u As[2][128*32];
    __shared__ bf16u Bs[2][128*32];
    const int tid  = threadIdx.x;
    const int lane = tid & 63;
    const int wave = tid >> 6;
    const int wr = wave >> 1, wc = wave & 1;
    const int lr = lane & 15;
    const int quad = lane >> 4;

    const int nwg  = gridDim.x * gridDim.y;
    const int fblk = blockIdx.y * gridDim.x + blockIdx.x;
    const int vblk = (fblk & 7) * (nwg >> 3) + (fblk >> 3);
    const int m0 = (vblk / gridDim.x) * 128;
    const int n0 = (vblk % gridDim.x) * 128;

    f32x4 acc[4][4];
    #pragma unroll
    for (int i = 0; i < 4; i++)
        #pragma unroll
        for (int j = 0; j < 4; j++)
            acc[i][j] = (f32x4){0.f, 0.f, 0.f, 0.f};

    auto stage = [&](int k0, int bf) {
        #pragma unroll
        for (int r = 0; r < 2; r++) {
            int c = r * 256 + tid;              // 0..511 chunks of 16B
            int row = c >> 2;                   // 4 chunks per 64B row
            int col = ((c & 3) ^ (row & 3)) * 8; // XOR-swizzled source chunk
            gl_lds16(A  + (size_t)(m0 + row) * 768 + k0 + col,
                     (char*)&As[bf][0] + c * 16);
            gl_lds16(Bw + (size_t)(n0 + row) * 768 + k0 + col,
                     (char*)&Bs[bf][0] + c * 16);
        }
    };

    stage(0, 0);

    auto body = [&](int k0, int buf, bool do_stage) __attribute__((always_inline)) {
        __syncthreads();                   // tile k0 staged; prev compute done
        if (do_stage) stage(k0 + 32, buf ^ 1);
        bf16x8 af[4], bg[4];
        #pragma unroll
        for (int t = 0; t < 4; t++) {
            int ra = wr * 64 + t * 16 + lr;
            int rb = wc * 64 + t * 16 + lr;
            af[t] = *(const bf16x8*)(&As[buf][0] + ra * 32 + ((quad ^ (ra & 3)) * 8));
            bg[t] = *(const bf16x8*)(&Bs[buf][0] + rb * 32 + ((quad ^ (rb & 3)) * 8));
        }
        __builtin_amdgcn_s_setprio(1);
        #pragma unroll
        for (int i = 0; i < 4; i++)
            #pragma unroll
            for (int j = 0; j < 4; j++)
                acc[i][j] = __builtin_amdgcn_mfma_f32_16x16x32_bf16(
                    af[i], bg[j], acc[i][j], 0, 0, 0);
        __builtin_amdgcn_s_setprio(0);
    };

    #pragma unroll 1
    for (int k0 = 0; k0 < 768 - 64; k0 += 64) {
        body(k0,      0, true);
        body(k0 + 32, 1, true);
    }
    body(768 - 64, 0, true);
    body(768 - 32, 1, false);

    #pragma unroll
    for (int i = 0; i < 4; i++) {
        int mbase = m0 + wr * 64 + i * 16 + quad * 4;
        #pragma unroll
        for (int j = 0; j < 4; j++) {
            int n = n0 + wc * 64 + j * 16 + lr;
            float bv = bias[n];
            if (EPI == 0) {
                #pragma unroll
                for (int r = 0; r < 4; r++)
                    Cout[(size_t)(mbase + r) * 768 + n] = acc[i][j][r] + bv;
            } else {
                int t3  = n / 768;
                int rem = n - t3 * 768;
                int h   = rem >> 6;
                int dh  = rem & 63;
                int b   = mbase >> 12;      // all 4 r share b (mbase%4==0)
                int s0  = mbase & 4095;
                int bh  = b * H_ + h;
                if (t3 == 2) {
                    uint2 pk;
                    pk.x = f2bf_pk(acc[i][j][0] + bv, acc[i][j][1] + bv);
                    pk.y = f2bf_pk(acc[i][j][2] + bv, acc[i][j][3] + bv);
                    *(uint2*)(Vtb + ((size_t)bh * DH_ + dh) * S_ + s0) = pk;
                } else if (t3 == 0) {
                    #pragma unroll
                    for (int r = 0; r < 4; r++)
                        Qb[((size_t)bh * S_ + s0 + r) * DH_ + dh] =
                            f2bf((acc[i][j][r] + bv) * QSCALE_);
                } else {
                    #pragma unroll
                    for (int r = 0; r < 4; r++)
                        Kb[((size_t)bh * S_ + s0 + r) * DH_ + dh] =
                            f2bf(acc[i][j][r] + bv);
                }
            }
        }
    }
}

// ---------------------------------------------------------------- attention
// R6: kv-split to halve LDS read traffic (the measured limiter: R3 read
// 6.1 GB from LDS = 78 µs floor at 128 B/cy/CU; measured 112).
//  * 8 waves; waves 0-3 (group A) process keys [0,2048), waves 4-7 (group
//    B) keys [2048,4096) for the SAME 128 q-rows; each wave owns 32 rows.
//    Valid because fixed-max softmax is linear in kv: o=o_A+o_B, l=l_A+l_B,
//    combined through LDS at the end (2 barriers, one-time).
//  * KVBLK=32: per-iter per-wave LDS reads = 4KB K + 4KB V; traffic/wave
//    halves vs R3 (rows doubled). 2x2 (pingpong x group) buffers = 32KB ->
//    3 blocks/CU -> 24 waves/CU (R4's TLP failure avoided).
//  * K tile [32 keys][64 dh]: same 128B-row XOR swizzle as R3 (0 conflicts).
//  * V tile [64 dh][32 kv]: 64B rows; pair two dh-rows into a 128B super-row,
//    slot = (dh&1)*4 + kvchunk, stored at slot^(sr&7). Read slot-index ==
//    bank-slot-index; 64 lanes land 8 per 16B-slot = optimal for b128.
//  * P in-register via T12 permlane network (R3-verified call pattern).
__global__ __launch_bounds__(512, 6) void attn_kernel(
    const bf16u* __restrict__ Qb, const bf16u* __restrict__ Kb,
    const bf16u* __restrict__ Vtb, bf16u* __restrict__ A2)
{
    // [K: pp*8192 + g*4096 | V: 16384 + pp*8192 + g*4096], 32KB KV + 512B l
    __shared__ char Lds[33280];
    const int tid  = threadIdx.x;
    const int lane = tid & 63;
    const int w    = tid >> 6;          // 0..7
    const int grp  = w >> 2;            // 0: kv [0,2048), 1: kv [2048,4096)
    const int wq   = (w & 3) * 32;      // q-row base within block
    const int lr   = lane & 15;
    const int quad = lane >> 4;

    // XCD-bijective swizzle: 768 blocks, 96 per XCD (= 3 full bh panels)
    const int fblk = blockIdx.y * gridDim.x + blockIdx.x;
    const int vblk = (fblk & 7) * 96 + (fblk >> 3);
    const int q0   = (vblk & 31) * 128;
    const int bh   = vblk >> 5;

    const size_t kbase_g = (size_t)bh * S_ * DH_;
    const size_t vbase_g = (size_t)bh * DH_ * S_;

    // Q B-fragments: aq[rh][ks], qrows q0+wq+rh*16+lr, feats ks*32+quad*8
    bf16x8 aq[2][2];
    #pragma unroll
    for (int rh = 0; rh < 2; rh++) {
        const size_t qb = ((size_t)bh * S_ + q0 + wq + rh * 16 + lr) * DH_ + quad * 8;
        aq[rh][0] = *(const bf16x8*)(Qb + qb);
        aq[rh][1] = *(const bf16x8*)(Qb + qb + 32);
    }

    bf16x8 onesf;
    #pragma unroll
    for (int j = 0; j < 8; j++) onesf[j] = (short)0x3F80;  // bf16 1.0

    f32x4 o[2][4];       // C-layout: [qrow=rh*16+quad*4+r2][dh=nt*16+lr]
    f32x4 l_acc[2];
    #pragma unroll
    for (int rh = 0; rh < 2; rh++) {
        l_acc[rh] = (f32x4){0.f, 0.f, 0.f, 0.f};
        #pragma unroll
        for (int t = 0; t < 4; t++) o[rh][t] = (f32x4){0.f, 0.f, 0.f, 0.f};
    }

    // Hoisted LDS byte offsets.
    // K frag [key-tile ntk][dh-half ks]: row rk=ntk*16+lr (128B rows)
    int kaddr[2][2];
    #pragma unroll
    for (int ntk = 0; ntk < 2; ntk++) {
        int rk = ntk * 16 + lr;
        kaddr[ntk][0] = rk * 128 + ((quad ^ (rk & 7)) * 16);
        kaddr[ntk][1] = rk * 128 + (((4 + quad) ^ (rk & 7)) * 16);
    }
    // V frag [dh-tile nt]: dh-row rv=nt*16+lr, kv-chunk quad (pair-row swz)
    int vaddr[4];
    #pragma unroll
    for (int nt = 0; nt < 4; nt++) {
        int rv = nt * 16 + lr;
        int sr = rv >> 1;
        int slot = ((rv & 1) << 2) | quad;
        vaddr[nt] = sr * 128 + ((slot ^ (sr & 7)) * 16);
    }

    // stage super-step u's tile-pair into pingpong pp.
    // thread tid: K chunk (tid&255) + V chunk (tid&255) of group tid>>8.
    auto stage = [&](int u, int pp) {
        const int g  = tid >> 8;
        const int c  = tid & 255;
        const int kv0 = g * (S_ / 2) + u * 32;
        // K: [32 keys][64 dh] rows of 8 chunks, XOR-swizzled source
        int krow = c >> 3;
        int kcol = ((c & 7) ^ (krow & 7)) * 8;
        gl_lds16(Kb + kbase_g + (size_t)(kv0 + krow) * DH_ + kcol,
                 Lds + pp * 8192 + g * 4096 + c * 16);
        // V: super-row sr = c>>3 holds dh rows {2sr, 2sr+1}; logical slot
        // lslot = rawslot ^ (sr&7): dh = 2sr + (lslot>>2), kv = (lslot&3)*8
        int sr = c >> 3;
        int lslot = (c & 7) ^ (sr & 7);
        int dh  = sr * 2 + (lslot >> 2);
        int kvc = (lslot & 3) * 8;
        gl_lds16(Vtb + vbase_g + (size_t)dh * S_ + kv0 + kvc,
                 Lds + 16384 + pp * 8192 + g * 4096 + c * 16);
    };

    stage(0, 0);

    // one super-step: each group computes its own 32-key tile
    auto body = [&](int u, int pp, bool do_stage) __attribute__((always_inline)) {
        __syncthreads();                  // pair `u` staged; prev compute done
        if (do_stage) stage(u + 1, pp ^ 1);

        const char* Kbuf = Lds + pp * 8192 + grp * 4096;
        const char* Vbuf = Lds + 16384 + pp * 8192 + grp * 4096;

        // S^T = K @ Q^T  (exp2-scaled).  C[m=key_local][n=qrow_local]
        f32x4 sc[2][2];
        __builtin_amdgcn_s_setprio(1);
        #pragma unroll
        for (int ntk = 0; ntk < 2; ntk++) {
            const bf16x8 bk0 = *(const bf16x8*)(Kbuf + kaddr[ntk][0]);
            const bf16x8 bk1 = *(const bf16x8*)(Kbuf + kaddr[ntk][1]);
            #pragma unroll
            for (int rh = 0; rh < 2; rh++) {
                f32x4 s = (f32x4){0.f, 0.f, 0.f, 0.f};
                s = __builtin_amdgcn_mfma_f32_16x16x32_bf16(bk0, aq[rh][0], s, 0, 0, 0);
                s = __builtin_amdgcn_mfma_f32_16x16x32_bf16(bk1, aq[rh][1], s, 0, 0, 0);
                sc[rh][ntk] = s;
            }
        }
        __builtin_amdgcn_s_setprio(0);

        // P = exp2(S): pack to bf16 pairs, all in-register
        unsigned W[2][2][2];
        #pragma unroll
        for (int rh = 0; rh < 2; rh++) {
            #pragma unroll
            for (int ntk = 0; ntk < 2; ntk++) {
                float p0 = __builtin_amdgcn_exp2f(sc[rh][ntk][0]);
                float p1 = __builtin_amdgcn_exp2f(sc[rh][ntk][1]);
                float p2 = __builtin_amdgcn_exp2f(sc[rh][ntk][2]);
                float p3 = __builtin_amdgcn_exp2f(sc[rh][ntk][3]);
                W[rh][ntk][0] = __builtin_amdgcn_perm(__float_as_uint(p1),
                                                      __float_as_uint(p0), 0x07060302u);
                W[rh][ntk][1] = __builtin_amdgcn_perm(__float_as_uint(p3),
                                                      __float_as_uint(p2), 0x07060302u);
            }
        }

        // permlane network: (W[rh][0][b], W[rh][1][b]) -> (a[b], a[2+b])
        bf16x8 ap[2];
        #pragma unroll
        for (int rh = 0; rh < 2; rh++) {
            union { unsigned u4[4]; bf16x8 v; } Af;
            #pragma unroll
            for (int b = 0; b < 2; b++) {
                auto r1 = __builtin_amdgcn_permlane32_swap(
                    W[rh][0][b], W[rh][1][b], false, false);
                auto r2 = __builtin_amdgcn_permlane16_swap(
                    r1[0], r1[1], false, false);
                Af.u4[b]     = r2[0];
                Af.u4[2 + b] = r2[1];
            }
            ap[rh] = Af.v;
        }

        // O += P @ V ; l += P @ 1
        __builtin_amdgcn_s_setprio(1);
        #pragma unroll
        for (int rh = 0; rh < 2; rh++)
            l_acc[rh] = __builtin_amdgcn_mfma_f32_16x16x32_bf16(ap[rh], onesf, l_acc[rh], 0, 0, 0);
        #pragma unroll
        for (int nt = 0; nt < 4; nt++) {
            const bf16x8 bv = *(const bf16x8*)(Vbuf + vaddr[nt]);
            #pragma unroll
            for (int rh = 0; rh < 2; rh++)
                o[rh][nt] = __builtin_amdgcn_mfma_f32_16x16x32_bf16(ap[rh], bv, o[rh][nt], 0, 0, 0);
        }
        __builtin_amdgcn_s_setprio(0);
    };

    // 64 super-steps; x2 unroll so pp is a literal; explicit 2-step tail
    #pragma unroll 1
    for (int u = 0; u < 62; u += 2) {
        body(u,     0, true);
        body(u + 1, 1, true);
    }
    body(62, 0, true);
    body(63, 1, false);

    // ---- cross-group combine: o = o_A + o_B, l = l_A + l_B ----
    __syncthreads();                       // all compute done; LDS reusable
    float* LO = (float*)Lds;               // [128][64] f32 = 32KB
    float* LL = (float*)(Lds + 32768);     // [128] f32
    if (grp == 0) {
        #pragma unroll
        for (int rh = 0; rh < 2; rh++) {
            #pragma unroll
            for (int r2 = 0; r2 < 4; r2++)
                LL[wq + rh * 16 + quad * 4 + r2] = l_acc[rh][r2];
            #pragma unroll
            for (int nt = 0; nt < 4; nt++)
                #pragma unroll
                for (int r2 = 0; r2 < 4; r2++)
                    LO[(wq + rh * 16 + quad * 4 + r2) * 64 + nt * 16 + lr] =
                        o[rh][nt][r2];
        }
    }
    __syncthreads();
    if (grp == 1) {
        const int b = bh / H_, h = bh % H_;
        #pragma unroll
        for (int rh = 0; rh < 2; rh++) {
            float rl[4];
            #pragma unroll
            for (int r2 = 0; r2 < 4; r2++)
                rl[r2] = 1.0f / (l_acc[rh][r2] + LL[wq + rh * 16 + quad * 4 + r2]);
            #pragma unroll
            for (int nt = 0; nt < 4; nt++)
                #pragma unroll
                for (int r2 = 0; r2 < 4; r2++) {
                    int row = wq + rh * 16 + quad * 4 + r2;
                    int q = q0 + row;
                    float v = (o[rh][nt][r2] + LO[row * 64 + nt * 16 + lr]) * rl[r2];
                    A2[((size_t)b * S_ + q) * D_ + h * DH_ + nt * 16 + lr] = f2bf(v);
                }
        }
    }
}

// ---------------------------------------------------------------- launch
extern "C" void kernel_launch(void* const* d_in, const int* in_sizes, int n_in,
                              void* d_out, int out_size, void* d_ws, size_t ws_size,
                              hipStream_t stream) {
    const float* x     = (const float*)d_in[0];
    const float* W_qkv = (const float*)d_in[1];
    const float* b_qkv = (const float*)d_in[2];
    const float* W_out = (const float*)d_in[3];
    const float* b_out = (const float*)d_in[4];
    float* out = (float*)d_out;
    char* ws = (char*)d_ws;

    // workspace layout (bytes, all 256-aligned)
    bf16u* xb    = (bf16u*)(ws + 0);          // 8192*768*2  = 12582912
    bf16u* wqkvb = (bf16u*)(ws + 12582912);   // 2304*768*2  =  3538944
    bf16u* woutb = (bf16u*)(ws + 16121856);   //  768*768*2  =  1179648
    bf16u* Qb    = (bf16u*)(ws + 17301504);   // 24*4096*64*2 = 12582912
    bf16u* Kb    = (bf16u*)(ws + 29884416);
    bf16u* Vtb   = (bf16u*)(ws + 42467328);
    bf16u* A2    = (bf16u*)(ws + 55050240);   // 8192*768*2

    convert3_kernel<<<(N1Q_ + N2Q_ + N3Q_) / 256, 256, 0, stream>>>(
        x, W_qkv, W_out, xb, wqkvb, woutb);

    dim3 g1(NQKV_/128, M_/128);   // 18 x 64 = 1152 blocks (%8==0)
    gemm_kernel<1><<<g1, 256, 0, stream>>>(xb, wqkvb, b_qkv, nullptr, Qb, Kb, Vtb);

    dim3 g2(S_/128, BH_);         // 32 x 24 = 768 blocks, 512 thr, 3/CU
    attn_kernel<<<g2, 512, 0, stream>>>(Qb, Kb, Vtb, A2);

    dim3 g3(D_/128, M_/128);      // 6 x 64 = 384 blocks (%8==0)
    gemm_kernel<0><<<g3, 256, 0, stream>>>(A2, woutb, b_out, out, nullptr, nullptr, nullptr);
}

// Round 7
// 251.334 us; speedup vs baseline: 2.7256x; 2.7256x over previous
//
#include <hip/hip_runtime.h>
#include <hip/hip_bf16.h>
#include <stdint.h>

#define B_    2
#define S_    4096
#define D_    768
#define H_    12
#define DH_   64
#define BH_   (B_*H_)
#define M_    (B_*S_)       // 8192
#define NQKV_ 2304
// 1/sqrt(64) * log2(e): Q pre-scaled so softmax runs in exp2 space
#define QSCALE_ 0.18033688011112042f

typedef unsigned short bf16u;
typedef short bf16x8 __attribute__((ext_vector_type(8)));
typedef float f32x4 __attribute__((ext_vector_type(4)));

__device__ __forceinline__ bf16u f2bf(float f) {
    unsigned u = __float_as_uint(f);
    u += 0x7FFFu + ((u >> 16) & 1u);   // round-to-nearest-even
    return (bf16u)(u >> 16);
}

__device__ __forceinline__ unsigned f2bf_pk(float a, float b) {
    return (unsigned)f2bf(a) | ((unsigned)f2bf(b) << 16);
}

__device__ __forceinline__ void gl_lds16(const void* g, void* l) {
    __builtin_amdgcn_global_load_lds(
        (const __attribute__((address_space(1))) unsigned*)g,
        (__attribute__((address_space(3))) unsigned*)l, 16, 0, 0);
}

// ---------------------------------------------------------------- convert
// three tensors in one launch (boundaries are multiples of 256 quads)
#define N1Q_ 1572864   // x      quads
#define N2Q_  442368   // W_qkv  quads
#define N3Q_  147456   // W_out  quads
__global__ __launch_bounds__(256) void convert3_kernel(
    const float* __restrict__ s1, const float* __restrict__ s2,
    const float* __restrict__ s3, bf16u* __restrict__ d1,
    bf16u* __restrict__ d2, bf16u* __restrict__ d3)
{
    int i = blockIdx.x * 256 + threadIdx.x;
    const float* s; bf16u* d; int j;
    if (i < N1Q_)              { s = s1; d = d1; j = i; }
    else if (i < N1Q_ + N2Q_)  { s = s2; d = d2; j = i - N1Q_; }
    else                       { s = s3; d = d3; j = i - N1Q_ - N2Q_; }
    float4 v = ((const float4*)s)[j];
    ushort4 o;
    o.x = f2bf(v.x); o.y = f2bf(v.y); o.z = f2bf(v.z); o.w = f2bf(v.w);
    ((ushort4*)d)[j] = o;
}

// ---------------------------------------------------------------- GEMM
// (unchanged from R5: double-buffered, 1 barrier/k-step, XCD swizzle,
//  V packed uint2 in EPI=1 epilogue)
template<int EPI>
__global__ __launch_bounds__(256) void gemm_kernel(
    const bf16u* __restrict__ A, const bf16u* __restrict__ Bw,
    const float* __restrict__ bias, float* __restrict__ Cout,
    bf16u* __restrict__ Qb, bf16u* __restrict__ Kb, bf16u* __restrict__ Vtb)
{
    __shared__ bf16u As[2][128*32];
    __shared__ bf16u Bs[2][128*32];
    const int tid  = threadIdx.x;
    const int lane = tid & 63;
    const int wave = tid >> 6;
    const int wr = wave >> 1, wc = wave & 1;
    const int lr = lane & 15;
    const int quad = lane >> 4;

    const int nwg  = gridDim.x * gridDim.y;
    const int fblk = blockIdx.y * gridDim.x + blockIdx.x;
    const int vblk = (fblk & 7) * (nwg >> 3) + (fblk >> 3);
    const int m0 = (vblk / gridDim.x) * 128;
    const int n0 = (vblk % gridDim.x) * 128;

    f32x4 acc[4][4];
    #pragma unroll
    for (int i = 0; i < 4; i++)
        #pragma unroll
        for (int j = 0; j < 4; j++)
            acc[i][j] = (f32x4){0.f, 0.f, 0.f, 0.f};

    auto stage = [&](int k0, int bf) {
        #pragma unroll
        for (int r = 0; r < 2; r++) {
            int c = r * 256 + tid;              // 0..511 chunks of 16B
            int row = c >> 2;                   // 4 chunks per 64B row
            int col = ((c & 3) ^ (row & 3)) * 8; // XOR-swizzled source chunk
            gl_lds16(A  + (size_t)(m0 + row) * 768 + k0 + col,
                     (char*)&As[bf][0] + c * 16);
            gl_lds16(Bw + (size_t)(n0 + row) * 768 + k0 + col,
                     (char*)&Bs[bf][0] + c * 16);
        }
    };

    stage(0, 0);

    auto body = [&](int k0, int buf, bool do_stage) __attribute__((always_inline)) {
        __syncthreads();                   // tile k0 staged; prev compute done
        if (do_stage) stage(k0 + 32, buf ^ 1);
        bf16x8 af[4], bg[4];
        #pragma unroll
        for (int t = 0; t < 4; t++) {
            int ra = wr * 64 + t * 16 + lr;
            int rb = wc * 64 + t * 16 + lr;
            af[t] = *(const bf16x8*)(&As[buf][0] + ra * 32 + ((quad ^ (ra & 3)) * 8));
            bg[t] = *(const bf16x8*)(&Bs[buf][0] + rb * 32 + ((quad ^ (rb & 3)) * 8));
        }
        __builtin_amdgcn_s_setprio(1);
        #pragma unroll
        for (int i = 0; i < 4; i++)
            #pragma unroll
            for (int j = 0; j < 4; j++)
                acc[i][j] = __builtin_amdgcn_mfma_f32_16x16x32_bf16(
                    af[i], bg[j], acc[i][j], 0, 0, 0);
        __builtin_amdgcn_s_setprio(0);
    };

    #pragma unroll 1
    for (int k0 = 0; k0 < 768 - 64; k0 += 64) {
        body(k0,      0, true);
        body(k0 + 32, 1, true);
    }
    body(768 - 64, 0, true);
    body(768 - 32, 1, false);

    #pragma unroll
    for (int i = 0; i < 4; i++) {
        int mbase = m0 + wr * 64 + i * 16 + quad * 4;
        #pragma unroll
        for (int j = 0; j < 4; j++) {
            int n = n0 + wc * 64 + j * 16 + lr;
            float bv = bias[n];
            if (EPI == 0) {
                #pragma unroll
                for (int r = 0; r < 4; r++)
                    Cout[(size_t)(mbase + r) * 768 + n] = acc[i][j][r] + bv;
            } else {
                int t3  = n / 768;
                int rem = n - t3 * 768;
                int h   = rem >> 6;
                int dh  = rem & 63;
                int b   = mbase >> 12;      // all 4 r share b (mbase%4==0)
                int s0  = mbase & 4095;
                int bh  = b * H_ + h;
                if (t3 == 2) {
                    uint2 pk;
                    pk.x = f2bf_pk(acc[i][j][0] + bv, acc[i][j][1] + bv);
                    pk.y = f2bf_pk(acc[i][j][2] + bv, acc[i][j][3] + bv);
                    *(uint2*)(Vtb + ((size_t)bh * DH_ + dh) * S_ + s0) = pk;
                } else if (t3 == 0) {
                    #pragma unroll
                    for (int r = 0; r < 4; r++)
                        Qb[((size_t)bh * S_ + s0 + r) * DH_ + dh] =
                            f2bf((acc[i][j][r] + bv) * QSCALE_);
                } else {
                    #pragma unroll
                    for (int r = 0; r < 4; r++)
                        Kb[((size_t)bh * S_ + s0 + r) * DH_ + dh] =
                            f2bf(acc[i][j][r] + bv);
                }
            }
        }
    }
}

// ---------------------------------------------------------------- attention
// R7 = R6 kv-split with the register budget FIXED.
// R6 post-mortem: __launch_bounds__(512,6) -> 85-VGPR budget vs ~110 live
// state -> compiler spilled accumulators in the main loop -> 1.5GB scratch
// writes + 946MB fetches (L2 thrash) -> 541µs. Math was correct (absmax
// passed). Fix: __launch_bounds__(512,4) -> 128-VGPR budget, no spill,
// 2 blocks/CU = 16 waves/CU (more than R4's failed 12).
//  * 8 waves; waves 0-3 process keys [0,2048), waves 4-7 keys [2048,4096)
//    for the SAME 128 q-rows; each wave owns 32 rows. Fixed-max softmax is
//    linear in kv: o=o_A+o_B, l=l_A+l_B, combined via LDS at the end.
//  * KVBLK=32: per-wave LDS reads halve vs R3 (8KB/iter for 32 rows).
//  * K tile: R3's 128B-row XOR swizzle. V tile: pair-row slot swizzle.
__global__ __launch_bounds__(512, 4) void attn_kernel(
    const bf16u* __restrict__ Qb, const bf16u* __restrict__ Kb,
    const bf16u* __restrict__ Vtb, bf16u* __restrict__ A2)
{
    // [K: pp*8192 + g*4096 | V: 16384 + pp*8192 + g*4096], 32KB KV + 512B l
    __shared__ char Lds[33280];
    const int tid  = threadIdx.x;
    const int lane = tid & 63;
    const int w    = tid >> 6;          // 0..7
    const int grp  = w >> 2;            // 0: kv [0,2048), 1: kv [2048,4096)
    const int wq   = (w & 3) * 32;      // q-row base within block
    const int lr   = lane & 15;
    const int quad = lane >> 4;

    // XCD-bijective swizzle: 768 blocks, 96 per XCD (= 3 full bh panels)
    const int fblk = blockIdx.y * gridDim.x + blockIdx.x;
    const int vblk = (fblk & 7) * 96 + (fblk >> 3);
    const int q0   = (vblk & 31) * 128;
    const int bh   = vblk >> 5;

    const size_t kbase_g = (size_t)bh * S_ * DH_;
    const size_t vbase_g = (size_t)bh * DH_ * S_;

    // Q B-fragments: aq[rh][ks], qrows q0+wq+rh*16+lr, feats ks*32+quad*8
    bf16x8 aq[2][2];
    #pragma unroll
    for (int rh = 0; rh < 2; rh++) {
        const size_t qb = ((size_t)bh * S_ + q0 + wq + rh * 16 + lr) * DH_ + quad * 8;
        aq[rh][0] = *(const bf16x8*)(Qb + qb);
        aq[rh][1] = *(const bf16x8*)(Qb + qb + 32);
    }

    bf16x8 onesf;
    #pragma unroll
    for (int j = 0; j < 8; j++) onesf[j] = (short)0x3F80;  // bf16 1.0

    f32x4 o[2][4];       // C-layout: [qrow=rh*16+quad*4+r2][dh=nt*16+lr]
    f32x4 l_acc[2];
    #pragma unroll
    for (int rh = 0; rh < 2; rh++) {
        l_acc[rh] = (f32x4){0.f, 0.f, 0.f, 0.f};
        #pragma unroll
        for (int t = 0; t < 4; t++) o[rh][t] = (f32x4){0.f, 0.f, 0.f, 0.f};
    }

    // Hoisted LDS byte offsets.
    // K frag [key-tile ntk][dh-half ks]: row rk=ntk*16+lr (128B rows)
    int kaddr[2][2];
    #pragma unroll
    for (int ntk = 0; ntk < 2; ntk++) {
        int rk = ntk * 16 + lr;
        kaddr[ntk][0] = rk * 128 + ((quad ^ (rk & 7)) * 16);
        kaddr[ntk][1] = rk * 128 + (((4 + quad) ^ (rk & 7)) * 16);
    }
    // V frag [dh-tile nt]: dh-row rv=nt*16+lr, kv-chunk quad (pair-row swz)
    int vaddr[4];
    #pragma unroll
    for (int nt = 0; nt < 4; nt++) {
        int rv = nt * 16 + lr;
        int sr = rv >> 1;
        int slot = ((rv & 1) << 2) | quad;
        vaddr[nt] = sr * 128 + ((slot ^ (sr & 7)) * 16);
    }

    // stage super-step u's tile-pair into pingpong pp.
    auto stage = [&](int u, int pp) {
        const int g  = tid >> 8;
        const int c  = tid & 255;
        const int kv0 = g * (S_ / 2) + u * 32;
        // K: [32 keys][64 dh] rows of 8 chunks, XOR-swizzled source
        int krow = c >> 3;
        int kcol = ((c & 7) ^ (krow & 7)) * 8;
        gl_lds16(Kb + kbase_g + (size_t)(kv0 + krow) * DH_ + kcol,
                 Lds + pp * 8192 + g * 4096 + c * 16);
        // V: super-row sr = c>>3 holds dh rows {2sr, 2sr+1}; logical slot
        // lslot = rawslot ^ (sr&7): dh = 2sr + (lslot>>2), kv = (lslot&3)*8
        int sr = c >> 3;
        int lslot = (c & 7) ^ (sr & 7);
        int dh  = sr * 2 + (lslot >> 2);
        int kvc = (lslot & 3) * 8;
        gl_lds16(Vtb + vbase_g + (size_t)dh * S_ + kv0 + kvc,
                 Lds + 16384 + pp * 8192 + g * 4096 + c * 16);
    };

    stage(0, 0);

    // one super-step: each group computes its own 32-key tile
    auto body = [&](int u, int pp, bool do_stage) __attribute__((always_inline)) {
        __syncthreads();                  // pair `u` staged; prev compute done
        if (do_stage) stage(u + 1, pp ^ 1);

        const char* Kbuf = Lds + pp * 8192 + grp * 4096;
        const char* Vbuf = Lds + 16384 + pp * 8192 + grp * 4096;

        // S^T = K @ Q^T  (exp2-scaled).  C[m=key_local][n=qrow_local]
        f32x4 sc[2][2];
        __builtin_amdgcn_s_setprio(1);
        #pragma unroll
        for (int ntk = 0; ntk < 2; ntk++) {
            const bf16x8 bk0 = *(const bf16x8*)(Kbuf + kaddr[ntk][0]);
            const bf16x8 bk1 = *(const bf16x8*)(Kbuf + kaddr[ntk][1]);
            #pragma unroll
            for (int rh = 0; rh < 2; rh++) {
                f32x4 s = (f32x4){0.f, 0.f, 0.f, 0.f};
                s = __builtin_amdgcn_mfma_f32_16x16x32_bf16(bk0, aq[rh][0], s, 0, 0, 0);
                s = __builtin_amdgcn_mfma_f32_16x16x32_bf16(bk1, aq[rh][1], s, 0, 0, 0);
                sc[rh][ntk] = s;
            }
        }
        __builtin_amdgcn_s_setprio(0);

        // P = exp2(S): pack to bf16 pairs, all in-register
        unsigned W[2][2][2];
        #pragma unroll
        for (int rh = 0; rh < 2; rh++) {
            #pragma unroll
            for (int ntk = 0; ntk < 2; ntk++) {
                float p0 = __builtin_amdgcn_exp2f(sc[rh][ntk][0]);
                float p1 = __builtin_amdgcn_exp2f(sc[rh][ntk][1]);
                float p2 = __builtin_amdgcn_exp2f(sc[rh][ntk][2]);
                float p3 = __builtin_amdgcn_exp2f(sc[rh][ntk][3]);
                W[rh][ntk][0] = __builtin_amdgcn_perm(__float_as_uint(p1),
                                                      __float_as_uint(p0), 0x07060302u);
                W[rh][ntk][1] = __builtin_amdgcn_perm(__float_as_uint(p3),
                                                      __float_as_uint(p2), 0x07060302u);
            }
        }

        // permlane network: (W[rh][0][b], W[rh][1][b]) -> (a[b], a[2+b])
        bf16x8 ap[2];
        #pragma unroll
        for (int rh = 0; rh < 2; rh++) {
            union { unsigned u4[4]; bf16x8 v; } Af;
            #pragma unroll
            for (int b = 0; b < 2; b++) {
                auto r1 = __builtin_amdgcn_permlane32_swap(
                    W[rh][0][b], W[rh][1][b], false, false);
                auto r2 = __builtin_amdgcn_permlane16_swap(
                    r1[0], r1[1], false, false);
                Af.u4[b]     = r2[0];
                Af.u4[2 + b] = r2[1];
            }
            ap[rh] = Af.v;
        }

        // O += P @ V ; l += P @ 1
        __builtin_amdgcn_s_setprio(1);
        #pragma unroll
        for (int rh = 0; rh < 2; rh++)
            l_acc[rh] = __builtin_amdgcn_mfma_f32_16x16x32_bf16(ap[rh], onesf, l_acc[rh], 0, 0, 0);
        #pragma unroll
        for (int nt = 0; nt < 4; nt++) {
            const bf16x8 bv = *(const bf16x8*)(Vbuf + vaddr[nt]);
            #pragma unroll
            for (int rh = 0; rh < 2; rh++)
                o[rh][nt] = __builtin_amdgcn_mfma_f32_16x16x32_bf16(ap[rh], bv, o[rh][nt], 0, 0, 0);
        }
        __builtin_amdgcn_s_setprio(0);
    };

    // 64 super-steps; x2 unroll so pp is a literal; explicit 2-step tail
    #pragma unroll 1
    for (int u = 0; u < 62; u += 2) {
        body(u,     0, true);
        body(u + 1, 1, true);
    }
    body(62, 0, true);
    body(63, 1, false);

    // ---- cross-group combine: o = o_A + o_B, l = l_A + l_B ----
    __syncthreads();                       // all compute done; LDS reusable
    float* LO = (float*)Lds;               // [128][64] f32 = 32KB
    float* LL = (float*)(Lds + 32768);     // [128] f32
    if (grp == 0) {
        #pragma unroll
        for (int rh = 0; rh < 2; rh++) {
            #pragma unroll
            for (int r2 = 0; r2 < 4; r2++)
                LL[wq + rh * 16 + quad * 4 + r2] = l_acc[rh][r2];
            #pragma unroll
            for (int nt = 0; nt < 4; nt++)
                #pragma unroll
                for (int r2 = 0; r2 < 4; r2++)
                    LO[(wq + rh * 16 + quad * 4 + r2) * 64 + nt * 16 + lr] =
                        o[rh][nt][r2];
        }
    }
    __syncthreads();
    if (grp == 1) {
        const int b = bh / H_, h = bh % H_;
        #pragma unroll
        for (int rh = 0; rh < 2; rh++) {
            float rl[4];
            #pragma unroll
            for (int r2 = 0; r2 < 4; r2++)
                rl[r2] = 1.0f / (l_acc[rh][r2] + LL[wq + rh * 16 + quad * 4 + r2]);
            #pragma unroll
            for (int nt = 0; nt < 4; nt++)
                #pragma unroll
                for (int r2 = 0; r2 < 4; r2++) {
                    int row = wq + rh * 16 + quad * 4 + r2;
                    int q = q0 + row;
                    float v = (o[rh][nt][r2] + LO[row * 64 + nt * 16 + lr]) * rl[r2];
                    A2[((size_t)b * S_ + q) * D_ + h * DH_ + nt * 16 + lr] = f2bf(v);
                }
        }
    }
}

// ---------------------------------------------------------------- launch
extern "C" void kernel_launch(void* const* d_in, const int* in_sizes, int n_in,
                              void* d_out, int out_size, void* d_ws, size_t ws_size,
                              hipStream_t stream) {
    const float* x     = (const float*)d_in[0];
    const float* W_qkv = (const float*)d_in[1];
    const float* b_qkv = (const float*)d_in[2];
    const float* W_out = (const float*)d_in[3];
    const float* b_out = (const float*)d_in[4];
    float* out = (float*)d_out;
    char* ws = (char*)d_ws;

    // workspace layout (bytes, all 256-aligned)
    bf16u* xb    = (bf16u*)(ws + 0);          // 8192*768*2  = 12582912
    bf16u* wqkvb = (bf16u*)(ws + 12582912);   // 2304*768*2  =  3538944
    bf16u* woutb = (bf16u*)(ws + 16121856);   //  768*768*2  =  1179648
    bf16u* Qb    = (bf16u*)(ws + 17301504);   // 24*4096*64*2 = 12582912
    bf16u* Kb    = (bf16u*)(ws + 29884416);
    bf16u* Vtb   = (bf16u*)(ws + 42467328);
    bf16u* A2    = (bf16u*)(ws + 55050240);   // 8192*768*2

    convert3_kernel<<<(N1Q_ + N2Q_ + N3Q_) / 256, 256, 0, stream>>>(
        x, W_qkv, W_out, xb, wqkvb, woutb);

    dim3 g1(NQKV_/128, M_/128);   // 18 x 64 = 1152 blocks (%8==0)
    gemm_kernel<1><<<g1, 256, 0, stream>>>(xb, wqkvb, b_qkv, nullptr, Qb, Kb, Vtb);

    dim3 g2(S_/128, BH_);         // 32 x 24 = 768 blocks, 512 thr
    attn_kernel<<<g2, 512, 0, stream>>>(Qb, Kb, Vtb, A2);

    dim3 g3(D_/128, M_/128);      // 6 x 64 = 384 blocks (%8==0)
    gemm_kernel<0><<<g3, 256, 0, stream>>>(A2, woutb, b_out, out, nullptr, nullptr, nullptr);
}